// Round 3
// baseline (61.481 us; speedup 1.0000x reference)
//
#include <hip/hip_runtime.h>
#include <math.h>

// TensoIR physical rendering: N points x L lights -> 4 (N,3) outputs
// (rgb, wo_indir, wo_vis, indir), each linear->sRGB'd after the light sum.
//
// R3 changes vs R2 (latency-bound diagnosis):
//  - lane -> 4 CONSECUTIVE lights (i0 = 4*(lane+64j)): visibility read as
//    float4, indirect as 3x float4 -> 8 independent global vector loads per
//    point, ALL hoisted before compute (ILP latency hiding, 4x fewer load
//    instrs). Was: 32 scalar b32 loads, issued per-iteration.
//  - LDS light table re-laid as [k=light&3][q=light>>2] so per-k ds_read_b128
//    keeps the same benign stride-16B pattern as R2.
//  - per-point scalar loads issued before the staging __syncthreads.

#define PI_F     3.14159265358979323846f
#define FOURPI_F (4.0f * PI_F)
#define MAXL     512
#define MAXQ     (MAXL / 4)

__device__ __forceinline__ float fast_rcp(float x)  { float r; asm("v_rcp_f32 %0, %1" : "=v"(r) : "v"(x)); return r; }
__device__ __forceinline__ float fast_rsq(float x)  { float r; asm("v_rsq_f32 %0, %1" : "=v"(r) : "v"(x)); return r; }
__device__ __forceinline__ float fast_exp2(float x) { float r; asm("v_exp_f32 %0, %1" : "=v"(r) : "v"(x)); return r; }
__device__ __forceinline__ float fast_log2(float x) { float r; asm("v_log_f32 %0, %1" : "=v"(r) : "v"(x)); return r; }

__device__ __forceinline__ float lin2srgb(float x) {
  float lin = 12.92f * x;
  float xe  = fmaxf(x, 1e-8f);
  float e   = 1.055f * fast_exp2(fast_log2(xe) * (1.0f / 2.4f)) - 0.055f;
  return (x <= 0.0031308f) ? lin : e;
}

__device__ __forceinline__ float clamp01(float x) { return fminf(fmaxf(x, 0.0f), 1.0f); }
__device__ __forceinline__ float clampe(float x)  { return fminf(fmaxf(x, 1e-6f), 1.0f); }

// LC = compile-time light count (0 => runtime L, scalar fallback)
template <int LC>
__global__ void __launch_bounds__(256)
tensoir_render(const float* __restrict__ viewdirs,  // (N,3)
               const float* __restrict__ albedo,    // (N,3)
               const float* __restrict__ roughness, // (N,1)
               const float* __restrict__ fresnel,   // (N,3)
               const float* __restrict__ normal,    // (N,3)
               const float* __restrict__ light_dirs,// (L,3)
               const float* __restrict__ law,       // (L,)
               const float* __restrict__ env_rgbs,  // (L,3)
               const float* __restrict__ visibility,// (N,L,1)
               const float* __restrict__ indirect,  // (N,L,3)
               float* __restrict__ out,             // 4*N*3
               int N, int Lrt) {
  // light i lives at [i&3][i>>2]; per-k reads are stride-16B across lanes.
  __shared__ float4 s_dirw[4][MAXQ];  // normalized dir xyz, area weight
  __shared__ float4 s_env [4][MAXQ];  // env rgb, pad

  const int L = LC ? LC : Lrt;
  const int tid = threadIdx.x;
  const int lane = tid & 63;
  int n = blockIdx.x * 4 + (tid >> 6);
  if (n >= N) n = N - 1;  // duplicate work, identical writes (N%4!=0 tail)

  // ---- issue per-point scalar loads early (independent of staging) ----
  float vx = -viewdirs[3 * n + 0], vy = -viewdirs[3 * n + 1], vz = -viewdirs[3 * n + 2];
  float nx = normal[3 * n + 0], ny = normal[3 * n + 1], nz = normal[3 * n + 2];
  float rough0 = roughness[n];
  const float fr = fresnel[3 * n + 0], fg = fresnel[3 * n + 1], fb = fresnel[3 * n + 2];
  float ar0 = albedo[3 * n + 0], ag0 = albedo[3 * n + 1], ab0 = albedo[3 * n + 2];

  // ---- stage light table (per block) ----
  for (int l = tid; l < L && l < MAXL; l += 256) {
    float lx = light_dirs[3 * l + 0];
    float ly = light_dirs[3 * l + 1];
    float lz = light_dirs[3 * l + 2];
    float inv = fast_rsq(fmaxf(lx * lx + ly * ly + lz * lz, 1e-12f));
    s_dirw[l & 3][l >> 2] = make_float4(lx * inv, ly * inv, lz * inv, law[l]);
    s_env [l & 3][l >> 2] = make_float4(env_rgbs[3 * l + 0], env_rgbs[3 * l + 1],
                                        env_rgbs[3 * l + 2], 0.0f);
  }
  __syncthreads();

  // ---- per-point setup ----
  {
    float inv = fast_rsq(fmaxf(vx * vx + vy * vy + vz * vz, 1e-12f));
    vx *= inv; vy *= inv; vz *= inv;
  }
  {
    float inv = fast_rsq(fmaxf(nx * nx + ny * ny + nz * nz, 1e-12f));
    nx *= inv; ny *= inv; nz *= inv;
  }
  const float rough  = clamp01(rough0 * 0.9f + 0.09f);
  const float alpha  = rough * rough;
  const float alpha2 = alpha * alpha;
  const float a2m1   = alpha2 - 1.0f;
  const float kk     = (alpha + 2.0f * rough + 1.0f) * 0.125f;
  const float onemk  = 1.0f - kk;

  const float omfr = 1.0f - fr, omfg = 1.0f - fg, omfb = 1.0f - fb;
  const float ar = clamp01(ar0) * (1.0f / PI_F);
  const float ag = clamp01(ag0) * (1.0f / PI_F);
  const float ab = clamp01(ab0) * (1.0f / PI_F);

  const float NoV0 = vx * nx + vy * ny + vz * nz;
  const float sgn  = (NoV0 >= 0.0f) ? 1.0f : -1.0f;
  const float Nfx = nx * sgn, Nfy = ny * sgn, Nfz = nz * sgn;
  const float NoV  = clampe(fabsf(NoV0));
  const float nom1 = NoV * onemk + kk;

  // 9 accumulators: {wo_indir, wo_vis, indir} x {r,g,b}; rgb = wo_indir+indir.
  float s1r = 0, s1g = 0, s1b = 0;
  float s2r = 0, s2g = 0, s2b = 0;
  float s3r = 0, s3g = 0, s3b = 0;

  const float* visrow = visibility + (size_t)n * L;
  const float* indrow = indirect + (size_t)n * L * 3;

#define LIGHT_BODY(dw, ev, visv, ir_, ig_, ib_)                                 \
  do {                                                                          \
    const float cosine = fmaxf((dw).x * nx + (dw).y * ny + (dw).z * nz, 0.0f);  \
    const bool  mask   = cosine > 1e-6f;                                        \
    const float w      = cosine * (dw).w;                                       \
    const float hx = (dw).x + vx, hy = (dw).y + vy, hz = (dw).z + vz;           \
    const float hinv = fast_rsq(fmaxf(hx * hx + hy * hy + hz * hz, 1e-12f));    \
    const float NoL = clampe(Nfx * (dw).x + Nfy * (dw).y + Nfz * (dw).z);       \
    const float NoH = clampe((Nfx * hx + Nfy * hy + Nfz * hz) * hinv);          \
    const float VoH = clampe((vx * hx + vy * hy + vz * hz) * hinv);             \
    const float FMi = (-5.55473f * VoH - 6.98316f) * VoH;                       \
    const float p2  = fast_exp2(FMi);                                           \
    const float nom0 = NoH * NoH * a2m1 + 1.0f;                                 \
    const float nom2 = NoL * onemk + kk;                                        \
    const float nom  = fminf(fmaxf(FOURPI_F * nom0 * nom0 * nom1 * nom2, 1e-6f),\
                             FOURPI_F);                                         \
    const float ss   = alpha2 * fast_rcp(nom);                                  \
    const float br = ar + (fr + omfr * p2) * ss;                                \
    const float bg = ag + (fg + omfg * p2) * ss;                                \
    const float bb = ab + (fb + omfb * p2) * ss;                                \
    const float vism = mask ? (visv) : 0.0f;                                    \
    const float irm  = mask ? (ir_) : 0.0f;                                     \
    const float igm  = mask ? (ig_) : 0.0f;                                     \
    const float ibm  = mask ? (ib_) : 0.0f;                                     \
    const float twr = br * w, twg = bg * w, twb = bb * w;                       \
    s1r += twr * (vism * (ev).x); s1g += twg * (vism * (ev).y);                 \
    s1b += twb * (vism * (ev).z);                                               \
    s2r += twr * (ev).x; s2g += twg * (ev).y; s2b += twb * (ev).z;              \
    s3r += twr * irm;    s3g += twg * igm;    s3b += twb * ibm;                 \
  } while (0)

  if (LC == 512) {
    const float4* vis4 = (const float4*)visrow;   // 16B-aligned: n*512*4
    const float4* ind4 = (const float4*)indrow;   // 16B-aligned: n*1536*4
    const int q0 = lane;        // lights 4*q0 .. 4*q0+3
    const int q1 = lane + 64;   // lights 4*q1 .. 4*q1+3

    // ---- hoist ALL global loads for this point (8 independent float4) ----
    const float4 va = vis4[q0];
    const float4 vb = vis4[q1];
    const float4 ia0 = ind4[3 * q0 + 0];
    const float4 ia1 = ind4[3 * q0 + 1];
    const float4 ia2 = ind4[3 * q0 + 2];
    const float4 ib0 = ind4[3 * q1 + 0];
    const float4 ib1 = ind4[3 * q1 + 1];
    const float4 ib2 = ind4[3 * q1 + 2];

    {
      const float4 d0 = s_dirw[0][q0], e0 = s_env[0][q0];
      const float4 d1 = s_dirw[1][q0], e1 = s_env[1][q0];
      const float4 d2 = s_dirw[2][q0], e2 = s_env[2][q0];
      const float4 d3 = s_dirw[3][q0], e3 = s_env[3][q0];
      LIGHT_BODY(d0, e0, va.x, ia0.x, ia0.y, ia0.z);
      LIGHT_BODY(d1, e1, va.y, ia0.w, ia1.x, ia1.y);
      LIGHT_BODY(d2, e2, va.z, ia1.z, ia1.w, ia2.x);
      LIGHT_BODY(d3, e3, va.w, ia2.y, ia2.z, ia2.w);
    }
    {
      const float4 d0 = s_dirw[0][q1], e0 = s_env[0][q1];
      const float4 d1 = s_dirw[1][q1], e1 = s_env[1][q1];
      const float4 d2 = s_dirw[2][q1], e2 = s_env[2][q1];
      const float4 d3 = s_dirw[3][q1], e3 = s_env[3][q1];
      LIGHT_BODY(d0, e0, vb.x, ib0.x, ib0.y, ib0.z);
      LIGHT_BODY(d1, e1, vb.y, ib0.w, ib1.x, ib1.y);
      LIGHT_BODY(d2, e2, vb.z, ib1.z, ib1.w, ib2.x);
      LIGHT_BODY(d3, e3, vb.w, ib2.y, ib2.z, ib2.w);
    }
  } else {
    for (int i = lane; i < L; i += 64) {
      const float4 dw = s_dirw[i & 3][i >> 2];
      const float4 ev = s_env [i & 3][i >> 2];
      const float visv = visrow[i];
      const float ir = indrow[3 * i + 0];
      const float ig = indrow[3 * i + 1];
      const float ib = indrow[3 * i + 2];
      LIGHT_BODY(dw, ev, visv, ir, ig, ib);
    }
  }
#undef LIGHT_BODY

#define WAVE_RED(v)                 \
  do {                              \
    v += __shfl_xor(v, 32);         \
    v += __shfl_xor(v, 16);         \
    v += __shfl_xor(v, 8);          \
    v += __shfl_xor(v, 4);          \
    v += __shfl_xor(v, 2);          \
    v += __shfl_xor(v, 1);          \
  } while (0)
  WAVE_RED(s1r); WAVE_RED(s1g); WAVE_RED(s1b);
  WAVE_RED(s2r); WAVE_RED(s2g); WAVE_RED(s2b);
  WAVE_RED(s3r); WAVE_RED(s3g); WAVE_RED(s3b);
#undef WAVE_RED

  if (lane == 0) {
    const size_t stride = (size_t)3 * N;
    float* o0 = out + 3 * (size_t)n;             // rgb
    float* o1 = o0 + stride;                     // wo_indir
    float* o2 = o1 + stride;                     // wo_vis
    float* o3 = o2 + stride;                     // indir
    o0[0] = lin2srgb(clamp01(s1r + s3r));
    o0[1] = lin2srgb(clamp01(s1g + s3g));
    o0[2] = lin2srgb(clamp01(s1b + s3b));
    o1[0] = lin2srgb(s1r); o1[1] = lin2srgb(s1g); o1[2] = lin2srgb(s1b);
    o2[0] = lin2srgb(s2r); o2[1] = lin2srgb(s2g); o2[2] = lin2srgb(s2b);
    o3[0] = lin2srgb(s3r); o3[1] = lin2srgb(s3g); o3[2] = lin2srgb(s3b);
  }
}

extern "C" void kernel_launch(void* const* d_in, const int* in_sizes, int n_in,
                              void* d_out, int out_size, void* d_ws, size_t ws_size,
                              hipStream_t stream) {
  const float* viewdirs   = (const float*)d_in[0];
  const float* albedo     = (const float*)d_in[1];
  const float* roughness  = (const float*)d_in[2];
  const float* fresnel    = (const float*)d_in[3];
  const float* normal     = (const float*)d_in[4];
  const float* light_dirs = (const float*)d_in[5];
  const float* law        = (const float*)d_in[6];
  const float* env_rgbs   = (const float*)d_in[7];
  const float* visibility = (const float*)d_in[8];
  const float* indirect   = (const float*)d_in[9];
  float* out = (float*)d_out;

  const int N = in_sizes[0] / 3;
  const int L = in_sizes[6];   // light_area_weight is (L,)

  dim3 block(256);
  dim3 grid((N + 3) / 4);  // 4 points (waves) per block

  if (L == 512) {
    hipLaunchKernelGGL(tensoir_render<512>, grid, block, 0, stream,
                       viewdirs, albedo, roughness, fresnel, normal,
                       light_dirs, law, env_rgbs, visibility, indirect,
                       out, N, L);
  } else {
    hipLaunchKernelGGL(tensoir_render<0>, grid, block, 0, stream,
                       viewdirs, albedo, roughness, fresnel, normal,
                       light_dirs, law, env_rgbs, visibility, indirect,
                       out, N, L);
  }
}

// Round 4
// 52.706 us; speedup vs baseline: 1.1665x; 1.1665x over previous
//
#include <hip/hip_runtime.h>
#include <math.h>

// TensoIR physical rendering: N points x L lights -> 4 (N,3) outputs
// (rgb, wo_indir, wo_vis, indir), each linear->sRGB'd after the light sum.
//
// R4 changes vs R2 (R3's consecutive-light layout regressed -> reverted):
//  - algebraic VALU cut: with unit L,V,N:  V.h = 1+LoV, Nf.h = sgn*cos0+|NoV|,
//    |h|^2 = 2+2*LoV  => only TWO dot products per pair (cos0, LoV); NoL
//    reuses cos0. c1 = 4pi*nom1 hoisted (wave-uniform). ~75 -> ~56 ops/pair.
//  - full unroll of the 8-iteration light loop (stride-64 lane mapping kept:
//    vis loads are dense 4B/lane, ind loads dense 12B/lane -> perfect
//    coalescing, scheduler free to hoist loads across iterations).

#define PI_F     3.14159265358979323846f
#define FOURPI_F (4.0f * PI_F)
#define MAXL     512

__device__ __forceinline__ float fast_rcp(float x)  { float r; asm("v_rcp_f32 %0, %1" : "=v"(r) : "v"(x)); return r; }
__device__ __forceinline__ float fast_rsq(float x)  { float r; asm("v_rsq_f32 %0, %1" : "=v"(r) : "v"(x)); return r; }
__device__ __forceinline__ float fast_exp2(float x) { float r; asm("v_exp_f32 %0, %1" : "=v"(r) : "v"(x)); return r; }
__device__ __forceinline__ float fast_log2(float x) { float r; asm("v_log_f32 %0, %1" : "=v"(r) : "v"(x)); return r; }

__device__ __forceinline__ float lin2srgb(float x) {
  float lin = 12.92f * x;
  float xe  = fmaxf(x, 1e-8f);
  float e   = 1.055f * fast_exp2(fast_log2(xe) * (1.0f / 2.4f)) - 0.055f;
  return (x <= 0.0031308f) ? lin : e;
}

__device__ __forceinline__ float clamp01(float x) { return fminf(fmaxf(x, 0.0f), 1.0f); }
__device__ __forceinline__ float clampe(float x)  { return fminf(fmaxf(x, 1e-6f), 1.0f); }

// LC = compile-time light count (0 => runtime L)
template <int LC>
__global__ void __launch_bounds__(256)
tensoir_render(const float* __restrict__ viewdirs,  // (N,3)
               const float* __restrict__ albedo,    // (N,3)
               const float* __restrict__ roughness, // (N,1)
               const float* __restrict__ fresnel,   // (N,3)
               const float* __restrict__ normal,    // (N,3)
               const float* __restrict__ light_dirs,// (L,3)
               const float* __restrict__ law,       // (L,)
               const float* __restrict__ env_rgbs,  // (L,3)
               const float* __restrict__ visibility,// (N,L,1)
               const float* __restrict__ indirect,  // (N,L,3)
               float* __restrict__ out,             // 4*N*3
               int N, int Lrt) {
  __shared__ float4 s_ld[MAXL];   // normalized light dir xyz, area weight
  __shared__ float4 s_env[MAXL];  // env rgb, pad

  const int L = LC ? LC : Lrt;
  const int tid = threadIdx.x;
  const int lane = tid & 63;
  int n = blockIdx.x * 4 + (tid >> 6);
  if (n >= N) n = N - 1;  // tail: duplicate work, identical writes

  // per-point scalar loads issued before staging (independent)
  float vx = -viewdirs[3 * n + 0], vy = -viewdirs[3 * n + 1], vz = -viewdirs[3 * n + 2];
  float nx = normal[3 * n + 0], ny = normal[3 * n + 1], nz = normal[3 * n + 2];
  float rough0 = roughness[n];
  const float fr = fresnel[3 * n + 0], fg = fresnel[3 * n + 1], fb = fresnel[3 * n + 2];
  float ar0 = albedo[3 * n + 0], ag0 = albedo[3 * n + 1], ab0 = albedo[3 * n + 2];

  // stage light table (per block)
  for (int l = tid; l < L && l < MAXL; l += 256) {
    float lx = light_dirs[3 * l + 0];
    float ly = light_dirs[3 * l + 1];
    float lz = light_dirs[3 * l + 2];
    float inv = fast_rsq(fmaxf(lx * lx + ly * ly + lz * lz, 1e-12f));
    s_ld[l]  = make_float4(lx * inv, ly * inv, lz * inv, law[l]);
    s_env[l] = make_float4(env_rgbs[3 * l + 0], env_rgbs[3 * l + 1],
                           env_rgbs[3 * l + 2], 0.0f);
  }
  __syncthreads();

  // ---- per-point (wave-uniform) setup ----
  {
    float inv = fast_rsq(fmaxf(vx * vx + vy * vy + vz * vz, 1e-12f));
    vx *= inv; vy *= inv; vz *= inv;
  }
  {
    float inv = fast_rsq(fmaxf(nx * nx + ny * ny + nz * nz, 1e-12f));
    nx *= inv; ny *= inv; nz *= inv;
  }
  const float rough  = clamp01(rough0 * 0.9f + 0.09f);
  const float alpha  = rough * rough;
  const float alpha2 = alpha * alpha;
  const float a2m1   = alpha2 - 1.0f;
  const float kk     = (alpha + 2.0f * rough + 1.0f) * 0.125f;
  const float onemk  = 1.0f - kk;

  const float omfr = 1.0f - fr, omfg = 1.0f - fg, omfb = 1.0f - fb;
  const float ar = clamp01(ar0) * (1.0f / PI_F);
  const float ag = clamp01(ag0) * (1.0f / PI_F);
  const float ab = clamp01(ab0) * (1.0f / PI_F);

  const float NoV0 = vx * nx + vy * ny + vz * nz;
  const float sgn  = (NoV0 >= 0.0f) ? 1.0f : -1.0f;
  const float aNoV = fabsf(NoV0);              // Nf . V (exact)
  const float NoV  = clampe(aNoV);
  const float nom1 = NoV * onemk + kk;
  const float c1   = FOURPI_F * nom1;          // hoisted constant factor

  // 9 accumulators: {wo_indir, wo_vis, indir} x {r,g,b}; rgb = wo_indir+indir.
  float s1r = 0, s1g = 0, s1b = 0;
  float s2r = 0, s2g = 0, s2b = 0;
  float s3r = 0, s3g = 0, s3b = 0;

  const float* visrow = visibility + (size_t)n * L;
  const float* indrow = indirect + (size_t)n * L * 3;

  auto body = [&](int i) {
    const float4 ld = s_ld[i];
    const float4 ev = s_env[i];
    const float visv = visrow[i];
    const float ir = indrow[3 * i + 0];
    const float ig = indrow[3 * i + 1];
    const float ib = indrow[3 * i + 2];

    // two dot products only
    const float cos0 = ld.x * nx + ld.y * ny + ld.z * nz;   // L . N
    const float LoV  = ld.x * vx + ld.y * vy + ld.z * vz;   // L . V

    const float cosine = fmaxf(cos0, 0.0f);
    const bool  mask   = cos0 > 1e-6f;
    const float w      = cosine * ld.w;

    const float NoL0 = sgn * cos0;                           // Nf . L
    const float NoL  = clampe(NoL0);

    const float h2   = fmaf(2.0f, LoV, 2.0f);                // |L+V|^2
    const float hinv = fast_rsq(fmaxf(h2, 1e-12f));
    const float VoH  = clampe((1.0f + LoV) * hinv);          // V.(L+V)/|h|
    const float NoH  = clampe((NoL0 + aNoV) * hinv);         // Nf.(L+V)/|h|

    const float FMi = (-5.55473f * VoH - 6.98316f) * VoH;
    const float p2  = fast_exp2(FMi);
    const float nom0 = fmaf(NoH * NoH, a2m1, 1.0f);
    const float nom2 = fmaf(NoL, onemk, kk);
    const float nom  = fminf(fmaxf(c1 * (nom0 * nom0) * nom2, 1e-6f), FOURPI_F);
    const float ss   = alpha2 * fast_rcp(nom);

    const float br = fmaf(fmaf(omfr, p2, fr), ss, ar);
    const float bg = fmaf(fmaf(omfg, p2, fg), ss, ag);
    const float bb = fmaf(fmaf(omfb, p2, fb), ss, ab);

    const float vism = mask ? visv : 0.0f;
    const float irm  = mask ? ir : 0.0f;
    const float igm  = mask ? ig : 0.0f;
    const float ibm  = mask ? ib : 0.0f;

    const float twr = br * w, twg = bg * w, twb = bb * w;

    s1r = fmaf(twr, vism * ev.x, s1r);
    s1g = fmaf(twg, vism * ev.y, s1g);
    s1b = fmaf(twb, vism * ev.z, s1b);
    s2r = fmaf(twr, ev.x, s2r);
    s2g = fmaf(twg, ev.y, s2g);
    s2b = fmaf(twb, ev.z, s2b);
    s3r = fmaf(twr, irm, s3r);
    s3g = fmaf(twg, igm, s3g);
    s3b = fmaf(twb, ibm, s3b);
  };

  if (LC) {
    constexpr int NITER = LC ? LC / 64 : 1;
#pragma unroll
    for (int j = 0; j < NITER; ++j) body(lane + 64 * j);
  } else {
    for (int i = lane; i < L; i += 64) body(i);
  }

#define WAVE_RED(v)                 \
  do {                              \
    v += __shfl_xor(v, 32);         \
    v += __shfl_xor(v, 16);         \
    v += __shfl_xor(v, 8);          \
    v += __shfl_xor(v, 4);          \
    v += __shfl_xor(v, 2);          \
    v += __shfl_xor(v, 1);          \
  } while (0)
  WAVE_RED(s1r); WAVE_RED(s1g); WAVE_RED(s1b);
  WAVE_RED(s2r); WAVE_RED(s2g); WAVE_RED(s2b);
  WAVE_RED(s3r); WAVE_RED(s3g); WAVE_RED(s3b);
#undef WAVE_RED

  if (lane == 0) {
    const size_t stride = (size_t)3 * N;
    float* o0 = out + 3 * (size_t)n;             // rgb
    float* o1 = o0 + stride;                     // wo_indir
    float* o2 = o1 + stride;                     // wo_vis
    float* o3 = o2 + stride;                     // indir
    o0[0] = lin2srgb(clamp01(s1r + s3r));
    o0[1] = lin2srgb(clamp01(s1g + s3g));
    o0[2] = lin2srgb(clamp01(s1b + s3b));
    o1[0] = lin2srgb(s1r); o1[1] = lin2srgb(s1g); o1[2] = lin2srgb(s1b);
    o2[0] = lin2srgb(s2r); o2[1] = lin2srgb(s2g); o2[2] = lin2srgb(s2b);
    o3[0] = lin2srgb(s3r); o3[1] = lin2srgb(s3g); o3[2] = lin2srgb(s3b);
  }
}

extern "C" void kernel_launch(void* const* d_in, const int* in_sizes, int n_in,
                              void* d_out, int out_size, void* d_ws, size_t ws_size,
                              hipStream_t stream) {
  const float* viewdirs   = (const float*)d_in[0];
  const float* albedo     = (const float*)d_in[1];
  const float* roughness  = (const float*)d_in[2];
  const float* fresnel    = (const float*)d_in[3];
  const float* normal     = (const float*)d_in[4];
  const float* light_dirs = (const float*)d_in[5];
  const float* law        = (const float*)d_in[6];
  const float* env_rgbs   = (const float*)d_in[7];
  const float* visibility = (const float*)d_in[8];
  const float* indirect   = (const float*)d_in[9];
  float* out = (float*)d_out;

  const int N = in_sizes[0] / 3;
  const int L = in_sizes[6];   // light_area_weight is (L,)

  dim3 block(256);
  dim3 grid((N + 3) / 4);  // 4 points (waves) per block

  if (L == 512) {
    hipLaunchKernelGGL(tensoir_render<512>, grid, block, 0, stream,
                       viewdirs, albedo, roughness, fresnel, normal,
                       light_dirs, law, env_rgbs, visibility, indirect,
                       out, N, L);
  } else {
    hipLaunchKernelGGL(tensoir_render<0>, grid, block, 0, stream,
                       viewdirs, albedo, roughness, fresnel, normal,
                       light_dirs, law, env_rgbs, visibility, indirect,
                       out, N, L);
  }
}